// Round 7
// baseline (364.832 us; speedup 1.0000x reference)
//
#include <hip/hip_runtime.h>
#include <hip/hip_fp16.h>

#define N_NODES 100000
#define E_EDGES 3200000
#define F_IN 11
#define F_H 64
#define F_E 32

#define BUCKETS ((N_NODES + 255) >> 8)   // 391 coarse buckets (dst>>8)
#define CAP 9216                         // slack bucket capacity (mean 8192, sigma~90 -> +11 sigma)
#define CHUNK_A 4096
#define NWG_A ((E_EDGES + CHUNK_A - 1) / CHUNK_A)  // 782

// ---------------- CSR construction (no counting pass; slack buckets) ----------------

__global__ void binA_kernel(const int* __restrict__ src,
                            const int* __restrict__ dst,
                            int* __restrict__ cursor,
                            unsigned int* __restrict__ pairs) {
    __shared__ int lh[BUCKETS];
    int t = threadIdx.x;
    for (int i = t; i < BUCKETS; i += 256) lh[i] = 0;
    __syncthreads();
    int e0 = blockIdx.x * CHUNK_A;
    int e1 = min(e0 + CHUNK_A, E_EDGES);
    for (int i = e0 + t; i < e1; i += 256)
        atomicAdd(&lh[dst[i] >> 8], 1);
    __syncthreads();
    for (int i = t; i < BUCKETS; i += 256) {
        int c = lh[i];
        lh[i] = (c > 0) ? (i * CAP + atomicAdd(&cursor[i], c)) : 0;
    }
    __syncthreads();
    for (int i = e0 + t; i < e1; i += 256) {
        int d = dst[i];
        int b = d >> 8;
        int pos = atomicAdd(&lh[b], 1);
        pairs[pos] = (unsigned int)src[i] | (((unsigned int)(d & 255)) << 17);
    }
}

__global__ void binB_kernel(const unsigned int* __restrict__ pairs,
                            const int* __restrict__ cursor,
                            int* __restrict__ deg_i,
                            int* __restrict__ offsets,
                            int* __restrict__ csr_src) {
    __shared__ int lhist[256];
    __shared__ int lscan[256];
    __shared__ int lcur[256];
    int b = blockIdx.x;
    int t = threadIdx.x;
    lhist[t] = 0;
    __syncthreads();
    int start = b * CAP;
    int end = start + cursor[b];
    for (int i = start + t; i < end; i += 256)
        atomicAdd(&lhist[pairs[i] >> 17], 1);
    __syncthreads();
    int cnt = lhist[t];
    lscan[t] = cnt;
    __syncthreads();
    int incl = cnt;
    for (int off = 1; off < 256; off <<= 1) {
        int tmp = (t >= off) ? lscan[t - off] : 0;
        __syncthreads();
        incl += tmp;
        lscan[t] = incl;
        __syncthreads();
    }
    int ex = start + incl - cnt;  // offset within slack csr layout
    int node = (b << 8) + t;
    if (node < N_NODES) {
        deg_i[node] = cnt;
        offsets[node] = ex;
    }
    lcur[t] = ex;
    __syncthreads();
    for (int i = start + t; i < end; i += 256) {
        unsigned int p = pairs[i];
        int pos = atomicAdd(&lcur[p >> 17], 1);
        csr_src[pos] = (int)(p & 0x1FFFFu);
    }
}

// ---------------- fp16 conversion of x ----------------
__global__ void convert_x_kernel(const float* __restrict__ x, __half* __restrict__ xh) {
    int tid = blockIdx.x * blockDim.x + threadIdx.x;
    if (tid >= N_NODES * 12) return;
    int n = tid / 12;
    int f = tid - n * 12;
    xh[tid] = __float2half((f < F_IN) ? x[n * F_IN + f] : 0.0f);
}

// ---------------- layer 1 ----------------

// gather via half2: 8 lanes/node, lanes 0..5 active (6 half2 = 12 halves/row)
__global__ void gather1_kernel(const int* __restrict__ csr_src,
                               const int* __restrict__ offsets,
                               const int* __restrict__ deg_i,
                               const __half2* __restrict__ xh2,
                               float* __restrict__ agg1) {
    int tid = blockIdx.x * blockDim.x + threadIdx.x;
    int n = tid >> 3;
    int f2 = tid & 7;
    if (n >= N_NODES || f2 >= 6) return;
    int start = offsets[n];
    int end = start + deg_i[n];
    float2 a0 = {0.f, 0.f}, a1 = {0.f, 0.f}, a2 = {0.f, 0.f}, a3 = {0.f, 0.f};
    int i = start;
    for (; i + 4 <= end; i += 4) {
        int s0 = csr_src[i], s1 = csr_src[i + 1], s2 = csr_src[i + 2], s3 = csr_src[i + 3];
        float2 v0 = __half22float2(xh2[s0 * 6 + f2]);
        float2 v1 = __half22float2(xh2[s1 * 6 + f2]);
        float2 v2 = __half22float2(xh2[s2 * 6 + f2]);
        float2 v3 = __half22float2(xh2[s3 * 6 + f2]);
        a0.x += v0.x; a0.y += v0.y;
        a1.x += v1.x; a1.y += v1.y;
        a2.x += v2.x; a2.y += v2.y;
        a3.x += v3.x; a3.y += v3.y;
    }
    for (; i < end; ++i) {
        float2 v = __half22float2(xh2[csr_src[i] * 6 + f2]);
        a0.x += v.x; a0.y += v.y;
    }
    float2 r;
    r.x = a0.x + a1.x + a2.x + a3.x;
    r.y = a0.y + a1.y + a2.y + a3.y;
    ((float2*)agg1)[n * 6 + f2] = r;   // agg1 padded to 12 floats/node
}

// h = relu(agg1/deg * W1l + x * W1r + b1) stored fp16; thread = (n, j<64)
__global__ void layer1_node_kernel(const float* __restrict__ x,
                                   const float* __restrict__ agg1,
                                   const int* __restrict__ deg_i,
                                   const float* __restrict__ W1l,
                                   const float* __restrict__ W1r,
                                   const float* __restrict__ b1,
                                   __half* __restrict__ hh) {
    int tid = blockIdx.x * blockDim.x + threadIdx.x;
    int n = tid >> 6;
    int j = tid & 63;
    if (n >= N_NODES) return;
    float invd = 1.0f / fmaxf((float)deg_i[n], 1.0f);
    float acc = b1[j];
    #pragma unroll
    for (int f = 0; f < F_IN; ++f) {
        float a = agg1[n * 12 + f] * invd;
        float xv = x[n * F_IN + f];
        acc += a * W1l[f * F_H + j] + xv * W1r[f * F_H + j];
    }
    hh[n * F_H + j] = __float2half(fmaxf(acc, 0.0f));
}

// ---------------- dual projection: p2 = h@W2l (sliced), r2 = h@W2r + b2 (sliced) ----
// thread = (n, j<32). Slices: a = cols 0..15, b = cols 16..31, each [N][16] fp16.
__global__ void proj2_dual_kernel(const __half2* __restrict__ hh2,
                                  const float* __restrict__ W2l,
                                  const float* __restrict__ W2r,
                                  const float* __restrict__ b2,
                                  __half* __restrict__ p2a, __half* __restrict__ p2b,
                                  __half* __restrict__ r2a, __half* __restrict__ r2b) {
    int tid = blockIdx.x * blockDim.x + threadIdx.x;
    int n = tid >> 5;
    int j = tid & 31;
    if (n >= N_NODES) return;
    const __half2* hrow = hh2 + n * 32;
    float accL = 0.0f, accR = 0.0f;
    #pragma unroll
    for (int k2 = 0; k2 < 32; ++k2) {
        float2 hv = __half22float2(hrow[k2]);
        accL += hv.x * W2l[(2 * k2) * F_E + j] + hv.y * W2l[(2 * k2 + 1) * F_E + j];
        accR += hv.x * W2r[(2 * k2) * F_E + j] + hv.y * W2r[(2 * k2 + 1) * F_E + j];
    }
    accR += b2[j];
    int jj = j & 15;
    __half* pd = (j < 16) ? p2a : p2b;
    __half* rd = (j < 16) ? r2a : r2b;
    pd[n * 16 + jj] = __float2half(accL);
    rd[n * 16 + jj] = __float2half(accR);
}

// ---------------- layer 2 slice pass: gather mean over L2-resident 3.2MB slice ----
// 8 lanes/node, each lane owns one half2 (2 features) of the 16-feature slice.
__global__ void layer2_pass_kernel(const int* __restrict__ csr_src,
                                   const int* __restrict__ offsets,
                                   const int* __restrict__ deg_i,
                                   const __half2* __restrict__ p2s,  // [N][8] half2
                                   const __half2* __restrict__ r2s,  // [N][8] half2
                                   float2* __restrict__ embs) {      // [N][8] float2
    int tid = blockIdx.x * blockDim.x + threadIdx.x;
    int n = tid >> 3;
    int l = tid & 7;
    if (n >= N_NODES) return;
    int start = offsets[n];
    int cnt = deg_i[n];
    int end = start + cnt;
    float2 a0 = {0.f, 0.f}, a1 = {0.f, 0.f}, a2 = {0.f, 0.f}, a3 = {0.f, 0.f};
    int i = start;
    for (; i + 8 <= end; i += 8) {
        int s0 = csr_src[i],     s1 = csr_src[i + 1], s2 = csr_src[i + 2], s3 = csr_src[i + 3];
        int s4 = csr_src[i + 4], s5 = csr_src[i + 5], s6 = csr_src[i + 6], s7 = csr_src[i + 7];
        float2 v0 = __half22float2(p2s[s0 * 8 + l]);
        float2 v1 = __half22float2(p2s[s1 * 8 + l]);
        float2 v2 = __half22float2(p2s[s2 * 8 + l]);
        float2 v3 = __half22float2(p2s[s3 * 8 + l]);
        float2 v4 = __half22float2(p2s[s4 * 8 + l]);
        float2 v5 = __half22float2(p2s[s5 * 8 + l]);
        float2 v6 = __half22float2(p2s[s6 * 8 + l]);
        float2 v7 = __half22float2(p2s[s7 * 8 + l]);
        a0.x += v0.x + v4.x; a0.y += v0.y + v4.y;
        a1.x += v1.x + v5.x; a1.y += v1.y + v5.y;
        a2.x += v2.x + v6.x; a2.y += v2.y + v6.y;
        a3.x += v3.x + v7.x; a3.y += v3.y + v7.y;
    }
    for (; i < end; ++i) {
        float2 v = __half22float2(p2s[csr_src[i] * 8 + l]);
        a0.x += v.x; a0.y += v.y;
    }
    float invd = 1.0f / fmaxf((float)cnt, 1.0f);
    float2 r = __half22float2(r2s[n * 8 + l]);
    float2 e;
    e.x = fmaxf((a0.x + a1.x + a2.x + a3.x) * invd + r.x, 0.0f);
    e.y = fmaxf((a0.y + a1.y + a2.y + a3.y) * invd + r.y, 0.0f);
    embs[n * 8 + l] = e;
}

// ---------------- merge emb slices + logits ----------------
// thread = n; reads embA/embB rows (64B each), writes emb row (128B) + 3 logits.
__global__ void logits_kernel(const float4* __restrict__ embA,  // [N][4] float4
                              const float4* __restrict__ embB,
                              const float* __restrict__ Wc,
                              const float* __restrict__ bc,
                              float4* __restrict__ emb_out,     // [N][8] float4
                              float* __restrict__ logits) {
    int n = blockIdx.x * blockDim.x + threadIdx.x;
    if (n >= N_NODES) return;
    float v[32];
    #pragma unroll
    for (int q = 0; q < 4; ++q) {
        float4 t = embA[n * 4 + q];
        v[4 * q + 0] = t.x; v[4 * q + 1] = t.y; v[4 * q + 2] = t.z; v[4 * q + 3] = t.w;
        emb_out[n * 8 + q] = t;
    }
    #pragma unroll
    for (int q = 0; q < 4; ++q) {
        float4 t = embB[n * 4 + q];
        v[16 + 4 * q + 0] = t.x; v[16 + 4 * q + 1] = t.y; v[16 + 4 * q + 2] = t.z; v[16 + 4 * q + 3] = t.w;
        emb_out[n * 8 + 4 + q] = t;
    }
    float c0 = bc[0], c1 = bc[1], c2 = bc[2];
    #pragma unroll
    for (int k = 0; k < 32; ++k) {
        c0 += v[k] * Wc[k * 3 + 0];
        c1 += v[k] * Wc[k * 3 + 1];
        c2 += v[k] * Wc[k * 3 + 2];
    }
    logits[n * 3 + 0] = c0;
    logits[n * 3 + 1] = c1;
    logits[n * 3 + 2] = c2;
}

extern "C" void kernel_launch(void* const* d_in, const int* in_sizes, int n_in,
                              void* d_out, int out_size, void* d_ws, size_t ws_size,
                              hipStream_t stream) {
    const float* x   = (const float*)d_in[0];
    const int*   ei  = (const int*)d_in[1];
    const float* W1l = (const float*)d_in[2];
    const float* W1r = (const float*)d_in[3];
    const float* b1  = (const float*)d_in[4];
    const float* W2l = (const float*)d_in[5];
    const float* W2r = (const float*)d_in[6];
    const float* b2  = (const float*)d_in[7];
    const float* Wc  = (const float*)d_in[8];
    const float* bc  = (const float*)d_in[9];

    const int* src = ei;
    const int* dst = ei + E_EDGES;

    float* out    = (float*)d_out;
    float* logits = out;
    float* emb    = out + (size_t)N_NODES * 3;

    // ws layout (4B units), total ~49.6 MB:
    //   deg_i   : N
    //   offsets : N
    //   cursor  : BUCKETS
    //   csr_src : BUCKETS*CAP (slack, 3.60M)
    //   region1 : BUCKETS*CAP (3.60M): pairs (binA..binB) -> hh 32N (layer1..proj2)
    //             -> embA 16N + embB 16N (pass1/2..logits)
    //   region2 : 32N: p2a|p2b|r2a|r2b, each [N][16] fp16 (8N units each)
    //   region3 : 18N: xh (6N) + agg1 (12N)  (convert..layer1)
    int* ws_i     = (int*)d_ws;
    int* deg_i    = ws_i;
    int* offsets  = ws_i + N_NODES;
    int* cursor   = ws_i + 2 * N_NODES;
    int* csr_src  = cursor + BUCKETS;
    int* region1  = csr_src + (size_t)BUCKETS * CAP;
    unsigned int* pairs = (unsigned int*)region1;
    __half* hh    = (__half*)region1;                          // 64N halves
    float*  embA  = (float*)region1;                           // [N][16] fp32
    float*  embB  = embA + (size_t)16 * N_NODES;
    int* region2  = region1 + (size_t)BUCKETS * CAP;
    __half* p2a   = (__half*)region2;                          // [N][16] fp16
    __half* p2b   = p2a + (size_t)16 * N_NODES;
    __half* r2a   = p2b + (size_t)16 * N_NODES;
    __half* r2b   = r2a + (size_t)16 * N_NODES;
    int* region3  = region2 + (size_t)8 * N_NODES * 4;         // 32N units
    __half* xh    = (__half*)region3;                          // 12N halves
    float* agg1   = (float*)(region3 + (size_t)6 * N_NODES);   // 12N floats

    hipMemsetAsync(cursor, 0, BUCKETS * sizeof(int), stream);

    const int BS = 256;

    binA_kernel<<<NWG_A, BS, 0, stream>>>(src, dst, cursor, pairs);
    binB_kernel<<<BUCKETS, BS, 0, stream>>>(pairs, cursor, deg_i, offsets, csr_src);

    convert_x_kernel<<<(N_NODES * 12 + BS - 1) / BS, BS, 0, stream>>>(x, xh);
    gather1_kernel<<<(N_NODES * 8 + BS - 1) / BS, BS, 0, stream>>>(
        csr_src, offsets, deg_i, (const __half2*)xh, agg1);
    layer1_node_kernel<<<(N_NODES * 64 + BS - 1) / BS, BS, 0, stream>>>(
        x, agg1, deg_i, W1l, W1r, b1, hh);
    proj2_dual_kernel<<<(N_NODES * 32 + BS - 1) / BS, BS, 0, stream>>>(
        (const __half2*)hh, W2l, W2r, b2, p2a, p2b, r2a, r2b);

    layer2_pass_kernel<<<(N_NODES * 8 + BS - 1) / BS, BS, 0, stream>>>(
        csr_src, offsets, deg_i, (const __half2*)p2a, (const __half2*)r2a, (float2*)embA);
    layer2_pass_kernel<<<(N_NODES * 8 + BS - 1) / BS, BS, 0, stream>>>(
        csr_src, offsets, deg_i, (const __half2*)p2b, (const __half2*)r2b, (float2*)embB);

    logits_kernel<<<(N_NODES + BS - 1) / BS, BS, 0, stream>>>(
        (const float4*)embA, (const float4*)embB, Wc, bc, (float4*)emb, logits);
}